// Round 1
// baseline (1379.950 us; speedup 1.0000x reference)
//
#include <hip/hip_runtime.h>
#include <math.h>

#define E_N 19
#define H_N 32
#define T_N 2048
#define B_N 64
#define G_N 128   // 4*H gates per chain
#define CHUNK 128 // timesteps staged into LDS at a time

__device__ __forceinline__ float fast_sigmoid(float x) {
    // 1/(1+e^-x); __expf handles overflow to inf -> result 0 correctly
    return __fdividef(1.0f, 1.0f + __expf(-x));
}
__device__ __forceinline__ float fast_tanh(float x) {
    // 2/(1+e^-2x) - 1; saturates correctly at +/-1
    return __fdividef(2.0f, 1.0f + __expf(-2.0f * x)) - 1.0f;
}

// One block (128 threads) per chain (b, e, dir). Thread g owns gate g.
__global__ __launch_bounds__(128, 4) void lstm_chain_kernel(
    const float* __restrict__ x,     // [B, T, E]
    const float* __restrict__ w_ih,  // [E, 2, 4H]
    const float* __restrict__ w_hh,  // [E, 2, 4H, H]
    const float* __restrict__ b_ih,  // [E, 2, 4H]
    const float* __restrict__ b_hh,  // [E, 2, 4H]
    float* __restrict__ hT)          // [B, E, 2, H]
{
    const int chain = blockIdx.x;          // b*(E*2) + e*2 + d
    const int b  = chain / (E_N * 2);
    const int ed = chain - b * (E_N * 2);  // e*2 + d
    const int e  = ed >> 1;
    const int d  = ed & 1;
    const int g  = threadIdx.x;            // gate index 0..127 (i:0-31 f:32-63 g:64-95 o:96-127)

    // Per-thread gate weights: w_hh[e][d][g][0..31] contiguous -> 8 x float4
    const float* wrow = w_hh + ((size_t)ed * G_N + g) * H_N;
    float w[H_N];
    #pragma unroll
    for (int k = 0; k < 8; ++k) {
        float4 v = ((const float4*)wrow)[k];
        w[4*k+0] = v.x; w[4*k+1] = v.y; w[4*k+2] = v.z; w[4*k+3] = v.w;
    }
    const float wih  = w_ih[(size_t)ed * G_N + g];
    const float bias = b_ih[(size_t)ed * G_N + g] + b_hh[(size_t)ed * G_N + g];

    __shared__ __align__(16) float h_lds[H_N];
    __shared__ float act[G_N];
    __shared__ float xbuf[CHUNK];

    if (g < H_N) h_lds[g] = 0.0f;
    float c = 0.0f;
    float h_last = 0.0f;

    const float* xbase = x + (size_t)b * T_N * E_N + e;
    __syncthreads();

    for (int t0 = 0; t0 < T_N; t0 += CHUNK) {
        // stage x chunk: logical time t0+g -> physical time (reversed for d==1)
        {
            const int tt    = t0 + g;
            const int tphys = d ? (T_N - 1 - tt) : tt;
            xbuf[g] = xbase[(size_t)tphys * E_N];
        }
        __syncthreads();

        for (int tl = 0; tl < CHUNK; ++tl) {
            const float xv = xbuf[tl];
            float gate = fmaf(xv, wih, bias);
            #pragma unroll
            for (int k = 0; k < 8; ++k) {
                const float4 hv = ((const float4*)h_lds)[k];  // broadcast read
                gate = fmaf(hv.x, w[4*k+0], gate);
                gate = fmaf(hv.y, w[4*k+1], gate);
                gate = fmaf(hv.z, w[4*k+2], gate);
                gate = fmaf(hv.w, w[4*k+3], gate);
            }
            // distribute activations: tanh for g-gate block [64,96), sigmoid otherwise
            const bool is_g = (g >= 64) && (g < 96);
            act[g] = is_g ? fast_tanh(gate) : fast_sigmoid(gate);
            __syncthreads();   // act ready; all h_lds reads complete

            if (g < H_N) {
                const float ai = act[g];
                const float af = act[g + 32];
                const float ag = act[g + 64];
                const float ao = act[g + 96];
                c = fmaf(af, c, ai * ag);
                h_last = ao * fast_tanh(c);
                h_lds[g] = h_last;
            }
            __syncthreads();   // h ready for next step
        }
    }

    if (g < H_N) {
        // hT[b][e][d][g] laid out so that [b][e][0:64] is the concat feature
        hT[((size_t)(b * E_N + e) * 2 + d) * H_N + g] = h_last;
    }
}

// LayerNorm over 64 feats per (b,e), mean over e, FC -> out[b]. One wave per b.
__global__ __launch_bounds__(64) void head_kernel(
    const float* __restrict__ hT,      // [B, E, 64]
    const float* __restrict__ ln_gamma,// [E, 64]
    const float* __restrict__ ln_beta, // [E, 64]
    const float* __restrict__ fc_w,    // [64]
    const float* __restrict__ fc_b,    // [1]
    float* __restrict__ out)           // [B]
{
    const int b = blockIdx.x;
    const int f = threadIdx.x; // 0..63

    float acc = 0.0f;
    for (int e = 0; e < E_N; ++e) {
        const float v = hT[(size_t)(b * E_N + e) * 64 + f];
        float s = v, s2 = v * v;
        #pragma unroll
        for (int off = 32; off > 0; off >>= 1) {
            s  += __shfl_xor(s,  off);
            s2 += __shfl_xor(s2, off);
        }
        const float mean = s * (1.0f / 64.0f);
        const float var  = s2 * (1.0f / 64.0f) - mean * mean;
        const float inv  = rsqrtf(var + 1e-5f);
        acc += (v - mean) * inv * ln_gamma[e * 64 + f] + ln_beta[e * 64 + f];
    }
    float contrib = (acc * (1.0f / (float)E_N)) * fc_w[f];
    #pragma unroll
    for (int off = 32; off > 0; off >>= 1) contrib += __shfl_xor(contrib, off);
    if (f == 0) out[b] = contrib + fc_b[0];
}

extern "C" void kernel_launch(void* const* d_in, const int* in_sizes, int n_in,
                              void* d_out, int out_size, void* d_ws, size_t ws_size,
                              hipStream_t stream) {
    const float* x        = (const float*)d_in[0];
    const float* w_ih     = (const float*)d_in[1];
    const float* w_hh     = (const float*)d_in[2];
    const float* b_ih     = (const float*)d_in[3];
    const float* b_hh     = (const float*)d_in[4];
    const float* ln_gamma = (const float*)d_in[5];
    const float* ln_beta  = (const float*)d_in[6];
    const float* fc_w     = (const float*)d_in[7];
    const float* fc_b     = (const float*)d_in[8];
    float* out = (float*)d_out;
    float* hT  = (float*)d_ws;  // B*E*2*H floats = 311296 bytes

    lstm_chain_kernel<<<B_N * E_N * 2, 128, 0, stream>>>(x, w_ih, w_hh, b_ih, b_hh, hT);
    head_kernel<<<B_N, 64, 0, stream>>>(hT, ln_gamma, ln_beta, fc_w, fc_b, out);
}

// Round 2
// 1355.790 us; speedup vs baseline: 1.0178x; 1.0178x over previous
//
#include <hip/hip_runtime.h>
#include <math.h>

#define E_N 19
#define H_N 32
#define T_N 2048
#define B_N 64
#define G_N 128            // 4*H gates per chain
#define WAVES_PER_BLOCK 4
#define XCHUNK 64          // timesteps staged per wave

__device__ __forceinline__ float fast_sigmoid(float x) {
    return __fdividef(1.0f, 1.0f + __expf(-x));
}

// One WAVE per chain (b, e, dir). Lane j and lane j+32 own hidden unit j:
//   lane j    (half=0): gate i_j (sigmoid) and gate g_j (tanh)
//   lane j+32 (half=1): gate f_j (sigmoid) and gate o_j (sigmoid)
// No __syncthreads anywhere — all exchange is intra-wave (shfl + per-wave LDS).
__global__ __launch_bounds__(64 * WAVES_PER_BLOCK, 2) void lstm_chain_kernel(
    const float* __restrict__ x,     // [B, T, E]
    const float* __restrict__ w_ih,  // [E, 2, 4H]
    const float* __restrict__ w_hh,  // [E, 2, 4H, H]
    const float* __restrict__ b_ih,  // [E, 2, 4H]
    const float* __restrict__ b_hh,  // [E, 2, 4H]
    float* __restrict__ hT)          // [B, E, 2, H]
{
    const int wave  = threadIdx.x >> 6;
    const int lane  = threadIdx.x & 63;
    const int chain = blockIdx.x * WAVES_PER_BLOCK + wave;   // b*(E*2) + e*2 + d
    const int b  = chain / (E_N * 2);
    const int ed = chain - b * (E_N * 2);
    const int e  = ed >> 1;
    const int d  = ed & 1;
    const int j    = lane & 31;
    const int half = lane >> 5;       // 0: i,g   1: f,o

    // gate rows this lane owns
    const int gate1 = j + 32 * half;        // i_j or f_j   (always sigmoid)
    const int gate2 = j + 64 + 32 * half;   // g_j or o_j   (tanh / sigmoid)

    // weights resident in registers: 2 rows x 32 = 16 float4
    const float* wr1 = w_hh + ((size_t)ed * G_N + gate1) * H_N;
    const float* wr2 = w_hh + ((size_t)ed * G_N + gate2) * H_N;
    float4 w1[8], w2[8];
    #pragma unroll
    for (int k = 0; k < 8; ++k) { w1[k] = ((const float4*)wr1)[k]; w2[k] = ((const float4*)wr2)[k]; }

    const float wih1 = w_ih[(size_t)ed * G_N + gate1];
    const float wih2 = w_ih[(size_t)ed * G_N + gate2];
    const float bias1 = b_ih[(size_t)ed * G_N + gate1] + b_hh[(size_t)ed * G_N + gate1];
    const float bias2 = b_ih[(size_t)ed * G_N + gate2] + b_hh[(size_t)ed * G_N + gate2];

    // gate2 activation: half0 -> tanh(x) = 2*sigmoid(2x)-1 ; half1 -> sigmoid(x)
    const float S2 = half ? 1.0f : 2.0f;
    const float A2 = half ? 1.0f : 2.0f;
    const float B2 = half ? 0.0f : -1.0f;

    __shared__ __align__(16) float h_lds[WAVES_PER_BLOCK][H_N];
    __shared__ float xbuf[WAVES_PER_BLOCK][XCHUNK];
    float* hme = h_lds[wave];
    float* xme = xbuf[wave];

    if (lane < H_N) hme[lane] = 0.0f;   // both halves j<32... lane<32 only: fine
    float c = 0.0f;
    float h = 0.0f;

    const float* xbase = x + (size_t)b * T_N * E_N + e;

    for (int t0 = 0; t0 < T_N; t0 += XCHUNK) {
        // stage 64 timesteps (one per lane); reversed time for d==1
        {
            const int tt    = t0 + lane;
            const int tphys = d ? (T_N - 1 - tt) : tt;
            xme[lane] = xbase[(size_t)tphys * E_N];
        }
        #pragma unroll 4
        for (int tl = 0; tl < XCHUNK; ++tl) {
            const float xv = xme[tl];   // wave-uniform broadcast read
            float a1a = fmaf(xv, wih1, bias1), a1b = 0.0f;
            float a2a = fmaf(xv, wih2, bias2), a2b = 0.0f;
            const float4* hv4 = (const float4*)hme;
            #pragma unroll
            for (int k = 0; k < 8; k += 2) {
                const float4 ha = hv4[k];
                const float4 hb = hv4[k + 1];
                a1a = fmaf(ha.x, w1[k].x, a1a);   a1a = fmaf(ha.y, w1[k].y, a1a);
                a1a = fmaf(ha.z, w1[k].z, a1a);   a1a = fmaf(ha.w, w1[k].w, a1a);
                a1b = fmaf(hb.x, w1[k+1].x, a1b); a1b = fmaf(hb.y, w1[k+1].y, a1b);
                a1b = fmaf(hb.z, w1[k+1].z, a1b); a1b = fmaf(hb.w, w1[k+1].w, a1b);
                a2a = fmaf(ha.x, w2[k].x, a2a);   a2a = fmaf(ha.y, w2[k].y, a2a);
                a2a = fmaf(ha.z, w2[k].z, a2a);   a2a = fmaf(ha.w, w2[k].w, a2a);
                a2b = fmaf(hb.x, w2[k+1].x, a2b); a2b = fmaf(hb.y, w2[k+1].y, a2b);
                a2b = fmaf(hb.z, w2[k+1].z, a2b); a2b = fmaf(hb.w, w2[k+1].w, a2b);
            }
            const float g1 = a1a + a1b;
            const float g2 = a2a + a2b;

            const float act1 = fast_sigmoid(g1);                    // i_j or f_j
            const float act2 = fmaf(A2, fast_sigmoid(S2 * g2), B2); // g_j or o_j

            const float oth1 = __shfl_xor(act1, 32);
            const float oth2 = __shfl_xor(act2, 32);

            const float iv = half ? oth1 : act1;
            const float fv = half ? act1 : oth1;
            const float gv = half ? oth2 : act2;
            const float ov = half ? act2 : oth2;

            c = fmaf(fv, c, iv * gv);
            const float tc = fmaf(2.0f, fast_sigmoid(2.0f * c), -1.0f); // tanh(c)
            h = ov * tc;
            hme[j] = h;   // both halves write identical value to same address
        }
    }

    if (!half) {
        hT[((size_t)(b * E_N + e) * 2 + d) * H_N + j] = h;
    }
}

// LayerNorm over 64 feats per (b,e), mean over e, FC -> out[b]. One wave per b.
__global__ __launch_bounds__(64) void head_kernel(
    const float* __restrict__ hT,      // [B, E, 64]
    const float* __restrict__ ln_gamma,// [E, 64]
    const float* __restrict__ ln_beta, // [E, 64]
    const float* __restrict__ fc_w,    // [64]
    const float* __restrict__ fc_b,    // [1]
    float* __restrict__ out)           // [B]
{
    const int b = blockIdx.x;
    const int f = threadIdx.x; // 0..63

    float acc = 0.0f;
    for (int e = 0; e < E_N; ++e) {
        const float v = hT[(size_t)(b * E_N + e) * 64 + f];
        float s = v, s2 = v * v;
        #pragma unroll
        for (int off = 32; off > 0; off >>= 1) {
            s  += __shfl_xor(s,  off);
            s2 += __shfl_xor(s2, off);
        }
        const float mean = s * (1.0f / 64.0f);
        const float var  = s2 * (1.0f / 64.0f) - mean * mean;
        const float inv  = rsqrtf(var + 1e-5f);
        acc += (v - mean) * inv * ln_gamma[e * 64 + f] + ln_beta[e * 64 + f];
    }
    float contrib = (acc * (1.0f / (float)E_N)) * fc_w[f];
    #pragma unroll
    for (int off = 32; off > 0; off >>= 1) contrib += __shfl_xor(contrib, off);
    if (f == 0) out[b] = contrib + fc_b[0];
}

extern "C" void kernel_launch(void* const* d_in, const int* in_sizes, int n_in,
                              void* d_out, int out_size, void* d_ws, size_t ws_size,
                              hipStream_t stream) {
    const float* x        = (const float*)d_in[0];
    const float* w_ih     = (const float*)d_in[1];
    const float* w_hh     = (const float*)d_in[2];
    const float* b_ih     = (const float*)d_in[3];
    const float* b_hh     = (const float*)d_in[4];
    const float* ln_gamma = (const float*)d_in[5];
    const float* ln_beta  = (const float*)d_in[6];
    const float* fc_w     = (const float*)d_in[7];
    const float* fc_b     = (const float*)d_in[8];
    float* out = (float*)d_out;
    float* hT  = (float*)d_ws;  // B*E*2*H floats

    const int n_chains = B_N * E_N * 2;                       // 2432
    const int n_blocks = n_chains / WAVES_PER_BLOCK;          // 608
    lstm_chain_kernel<<<n_blocks, 64 * WAVES_PER_BLOCK, 0, stream>>>(
        x, w_ih, w_hh, b_ih, b_hh, hT);
    head_kernel<<<B_N, 64, 0, stream>>>(hT, ln_gamma, ln_beta, fc_w, fc_b, out);
}